// Round 2
// baseline (141.256 us; speedup 1.0000x reference)
//
#include <hip/hip_runtime.h>

#define S_DIM 16
#define B_DIM 512
#define H_DIM 2048
#define EPS 1e-8f

typedef short bf16x8 __attribute__((ext_vector_type(8)));
typedef float f32x16 __attribute__((ext_vector_type(16)));

__device__ __forceinline__ unsigned short f2bf(float f) {
    union { float f; unsigned int u; } v; v.f = f;
    unsigned int u = v.u;
    unsigned int r = (u + 0x7fffu + ((u >> 16) & 1u)) >> 16;
    return (unsigned short)r;
}

__device__ __forceinline__ float dot4(const float4& a, const float4& b) {
    return a.x*b.x + a.y*b.y + a.z*b.z + a.w*b.w;
}

// ---------------- Kernel A: sims (one wave per (s,b) row) + W->bf16 ----------------
// Barrier-free streaming: each wave reduces one 8 KiB E row against its OG row
// (dot, e-norm, og-norm in one pass, 3 shfl butterflies). ~40 VGPR -> high
// occupancy, loads issue immediately. Blocks >= 2048 convert W to bf16.
__global__ __launch_bounds__(256) void sims_kernel(
    const float* __restrict__ OG, const float* __restrict__ E,
    const float* __restrict__ W, float* __restrict__ sims,
    unsigned short* __restrict__ Wb) {
    const int bid = blockIdx.x;
    if (bid < (S_DIM * B_DIM / 4)) {
        const int lane = threadIdx.x & 63;
        const int r = bid * 4 + (threadIdx.x >> 6);   // r = s*B + b
        const int b = r & (B_DIM - 1);
        const float4* e4  = (const float4*)E  + (size_t)r * (H_DIM / 4);
        const float4* og4 = (const float4*)OG + (size_t)b * (H_DIM / 4);
        float d = 0.f, n = 0.f, o = 0.f;
        #pragma unroll
        for (int i = 0; i < 8; ++i) {
            float4 e = e4[i * 64 + lane];
            float4 g = og4[i * 64 + lane];
            d += dot4(e, g); n += dot4(e, e); o += dot4(g, g);
        }
        #pragma unroll
        for (int m = 32; m >= 1; m >>= 1) {
            d += __shfl_xor(d, m, 64);
            n += __shfl_xor(n, m, 64);
            o += __shfl_xor(o, m, 64);
        }
        if (lane == 0) sims[r] = d / fmaxf(sqrtf(n) * sqrtf(o), EPS);
    } else {
        const int wb = bid - (S_DIM * B_DIM / 4);
        const int t = threadIdx.x;
        const float4* w4 = (const float4*)W;
        ushort4* wb4 = (ushort4*)Wb;
        #pragma unroll
        for (int j = 0; j < 8; ++j) {
            const size_t idx = (size_t)wb * 2048 + j * 256 + t;
            float4 v = w4[idx];
            ushort4 c;
            c.x = f2bf(v.x); c.y = f2bf(v.y); c.z = f2bf(v.z); c.w = f2bf(v.w);
            wb4[idx] = c;
        }
    }
}

// ---------------- Kernel B: weighted mean -> wrep (bf16) ----------------
// Block per b, thread per float4 column. 16 independent E loads issued before
// the (only) barrier; E is LLC-resident after kernel A (64 MiB < 256 MiB L3).
__global__ __launch_bounds__(512) void wmean_kernel(
    const float* __restrict__ E, const float* __restrict__ sims,
    unsigned short* __restrict__ wrep) {
    const int b = blockIdx.x;
    const int t = threadIdx.x;
    __shared__ float sl[S_DIM];
    const float4* e4 = (const float4*)E;
    float4 ev[S_DIM];
    #pragma unroll
    for (int s = 0; s < S_DIM; ++s)
        ev[s] = e4[((size_t)s * B_DIM + b) * (H_DIM / 4) + t];
    if (t < S_DIM) sl[t] = sims[t * B_DIM + b];
    __syncthreads();
    float x = 0.f, y = 0.f, z = 0.f, w = 0.f;
    #pragma unroll
    for (int s = 0; s < S_DIM; ++s) {
        const float sm = sl[s];
        x += sm * ev[s].x; y += sm * ev[s].y;
        z += sm * ev[s].z; w += sm * ev[s].w;
    }
    const float sc = 1.f / (float)S_DIM;
    ushort4 ob;
    ob.x = f2bf(x * sc); ob.y = f2bf(y * sc);
    ob.z = f2bf(z * sc); ob.w = f2bf(w * sc);
    ((ushort4*)wrep)[(size_t)b * (H_DIM / 4) + t] = ob;
}

// ---------------- Kernel C: out = wrep @ Wb^T + b  (bf16 MFMA 32x32x16) ----------------
// 64x64 tile / block, 4 waves each owning a 32x32 quadrant via
// mfma_f32_32x32x16_bf16: 2 ds_read_b128 per MFMA (8.2 kFLOP/read, 1.5x the
// 16x16x32 scheme). BK=64, double-buffered LDS, register prefetch, one
// barrier per K-iter. Grid 32x8 = 256 blocks = 1/CU.
__global__ __launch_bounds__(256) void gemm_kernel(
    const unsigned short* __restrict__ A, const unsigned short* __restrict__ Wb,
    const float* __restrict__ bias, float* __restrict__ out) {
    const int n0 = blockIdx.x * 64;
    const int m0 = blockIdx.y * 64;

    __shared__ unsigned short As[2][64][72];  // +8 pad: row stride 144 B
    __shared__ unsigned short Bs[2][64][72];

    const int t = threadIdx.x;
    const int lane = t & 63;
    const int wave = t >> 6;
    const int wm = (wave & 1) * 32;
    const int wn = (wave >> 1) * 32;

    // staging: 4 threads/row, 16 shorts (2 x uint4) each
    const int lr = t >> 2, lq = t & 3;
    const unsigned short* ap = A  + (size_t)(m0 + lr) * H_DIM + lq * 16;
    const unsigned short* bp = Wb + (size_t)(n0 + lr) * H_DIM + lq * 16;

    f32x16 acc = {0.f,0.f,0.f,0.f,0.f,0.f,0.f,0.f,
                  0.f,0.f,0.f,0.f,0.f,0.f,0.f,0.f};

    const int row = lane & 31;
    const int hi = lane >> 5;

    uint4 a0 = *(const uint4*)(ap);
    uint4 a1 = *(const uint4*)(ap + 8);
    uint4 b0 = *(const uint4*)(bp);
    uint4 b1 = *(const uint4*)(bp + 8);
    *(uint4*)&As[0][lr][lq * 16]     = a0;
    *(uint4*)&As[0][lr][lq * 16 + 8] = a1;
    *(uint4*)&Bs[0][lr][lq * 16]     = b0;
    *(uint4*)&Bs[0][lr][lq * 16 + 8] = b1;
    __syncthreads();

    for (int ki = 0; ki < 32; ++ki) {
        const int cur = ki & 1, nxt = cur ^ 1;
        if (ki + 1 < 32) {  // prefetch next K-tile into registers
            a0 = *(const uint4*)(ap + (ki + 1) * 64);
            a1 = *(const uint4*)(ap + (ki + 1) * 64 + 8);
            b0 = *(const uint4*)(bp + (ki + 1) * 64);
            b1 = *(const uint4*)(bp + (ki + 1) * 64 + 8);
        }
        #pragma unroll
        for (int ks = 0; ks < 4; ++ks) {
            // A frag: row = lane&31 (M), k = ks*16 + hi*8 + e
            bf16x8 af  = *(const bf16x8*)&As[cur][wm + row][ks * 16 + hi * 8];
            bf16x8 bfr = *(const bf16x8*)&Bs[cur][wn + row][ks * 16 + hi * 8];
            acc = __builtin_amdgcn_mfma_f32_32x32x16_bf16(af, bfr, acc, 0, 0, 0);
        }
        if (ki + 1 < 32) {
            *(uint4*)&As[nxt][lr][lq * 16]     = a0;
            *(uint4*)&As[nxt][lr][lq * 16 + 8] = a1;
            *(uint4*)&Bs[nxt][lr][lq * 16]     = b0;
            *(uint4*)&Bs[nxt][lr][lq * 16 + 8] = b1;
        }
        __syncthreads();
    }

    // D mapping (32x32, m74/m101): col = lane&31 (N), row = (r&3)+8*(r>>2)+4*hi (M)
    const int col = lane & 31;
    const float bias0 = bias[n0 + wn + col];
    #pragma unroll
    for (int r = 0; r < 16; ++r) {
        const int mr = (r & 3) + 8 * (r >> 2) + 4 * hi;
        out[(size_t)(m0 + wm + mr) * H_DIM + n0 + wn + col] = acc[r] + bias0;
    }
}

extern "C" void kernel_launch(void* const* d_in, const int* in_sizes, int n_in,
                              void* d_out, int out_size, void* d_ws, size_t ws_size,
                              hipStream_t stream) {
    const float* OG   = (const float*)d_in[0];
    const float* E    = (const float*)d_in[1];
    const float* W    = (const float*)d_in[2];
    const float* bias = (const float*)d_in[3];
    float* out = (float*)d_out;

    unsigned short* wrep = (unsigned short*)d_ws;                    // 2 MiB bf16
    unsigned short* Wb   = wrep + (size_t)B_DIM * H_DIM;             // 8 MiB bf16
    float* sims          = (float*)(Wb + (size_t)H_DIM * H_DIM);     // 32 KiB f32

    sims_kernel<<<(S_DIM * B_DIM / 4) + 512, 256, 0, stream>>>(OG, E, W, sims, Wb);
    wmean_kernel<<<B_DIM, 512, 0, stream>>>(E, sims, wrep);
    gemm_kernel<<<dim3(H_DIM / 64, B_DIM / 64), 256, 0, stream>>>(wrep, Wb, bias, out);
}

// Round 3
// 126.106 us; speedup vs baseline: 1.1201x; 1.1201x over previous
//
#include <hip/hip_runtime.h>

#define S_DIM 16
#define B_DIM 512
#define H_DIM 2048
#define EPS 1e-8f

typedef short bf16x8 __attribute__((ext_vector_type(8)));
typedef float f32x16 __attribute__((ext_vector_type(16)));

__device__ __forceinline__ unsigned short f2bf(float f) {
    union { float f; unsigned int u; } v; v.f = f;
    unsigned int u = v.u;
    unsigned int r = (u + 0x7fffu + ((u >> 16) & 1u)) >> 16;
    return (unsigned short)r;
}

__device__ __forceinline__ float dot4(const float4& a, const float4& b) {
    return a.x*b.x + a.y*b.y + a.z*b.z + a.w*b.w;
}

// ---------------- Kernel A: fused sims + weighted mean -> wrep, W->bf16 ----------------
// One block per b (512 thr), wave w owns E rows s=w and s=w+8. ALL loads (16
// float4 of E + 8 of OG per lane) issue up front -- no barrier gates them.
// Each wave loads the full OG row itself (8 KiB, L1-served after first wave;
// chunk order rotated per wave so concurrent waves touch different lines).
// Single barrier: cross-wave sum of weighted E via 64 KiB LDS. W->bf16 tail.
__global__ __launch_bounds__(512) void fused_kernel(
    const float* __restrict__ OG, const float* __restrict__ E,
    const float* __restrict__ W, unsigned short* __restrict__ wrep,
    unsigned short* __restrict__ Wb) {
    const int b = blockIdx.x;
    const int t = threadIdx.x;
    const int lane = t & 63;
    const int wave = t >> 6;

    __shared__ float4 buf[8][512];   // 64 KiB

    const float4* e4a = (const float4*)(E + ((size_t)wave * B_DIM + b) * H_DIM);
    const float4* e4b = (const float4*)(E + ((size_t)(wave + 8) * B_DIM + b) * H_DIM);
    const float4* og4 = (const float4*)(OG + (size_t)b * H_DIM);

    float4 ea[8], eb[8], og[8];
    #pragma unroll
    for (int i = 0; i < 8; ++i) {
        const int c = (i + wave) & 7;      // per-wave chunk rotation
        ea[i] = e4a[c * 64 + lane];
        eb[i] = e4b[c * 64 + lane];
        og[i] = og4[c * 64 + lane];
    }

    float da = 0.f, na = 0.f, db = 0.f, nb = 0.f, o2 = 0.f;
    #pragma unroll
    for (int i = 0; i < 8; ++i) {
        da += dot4(ea[i], og[i]);
        na += dot4(ea[i], ea[i]);
        db += dot4(eb[i], og[i]);
        nb += dot4(eb[i], eb[i]);
        o2 += dot4(og[i], og[i]);
    }
    #pragma unroll
    for (int m = 32; m >= 1; m >>= 1) {
        da += __shfl_xor(da, m, 64);
        na += __shfl_xor(na, m, 64);
        db += __shfl_xor(db, m, 64);
        nb += __shfl_xor(nb, m, 64);
        o2 += __shfl_xor(o2, m, 64);
    }
    const float onorm = sqrtf(o2);
    const float sima = da / fmaxf(sqrtf(na) * onorm, EPS);
    const float simb = db / fmaxf(sqrtf(nb) * onorm, EPS);

    #pragma unroll
    for (int i = 0; i < 8; ++i) {
        const int c = (i + wave) & 7;
        float4 v;
        v.x = ea[i].x * sima + eb[i].x * simb;
        v.y = ea[i].y * sima + eb[i].y * simb;
        v.z = ea[i].z * sima + eb[i].z * simb;
        v.w = ea[i].w * sima + eb[i].w * simb;
        buf[wave][c * 64 + lane] = v;
    }
    __syncthreads();

    float4 s = buf[0][t];
    #pragma unroll
    for (int w = 1; w < 8; ++w) {
        float4 v = buf[w][t];
        s.x += v.x; s.y += v.y; s.z += v.z; s.w += v.w;
    }
    const float sc = 1.f / (float)S_DIM;
    ushort4 ob;
    ob.x = f2bf(s.x * sc); ob.y = f2bf(s.y * sc);
    ob.z = f2bf(s.z * sc); ob.w = f2bf(s.w * sc);
    ((ushort4*)wrep)[(size_t)b * (H_DIM / 4) + t] = ob;

    const float4* w4 = (const float4*)W;
    #pragma unroll
    for (int j = 0; j < 4; ++j) {
        const size_t idx = (size_t)b * 2048 + j * 512 + t;
        float4 v = w4[idx];
        ushort4 c;
        c.x = f2bf(v.x); c.y = f2bf(v.y); c.z = f2bf(v.z); c.w = f2bf(v.w);
        ((ushort4*)Wb)[idx] = c;
    }
}

// ---------------- Kernel C: out = wrep @ Wb^T + b  (bf16 MFMA 32x32x16) ----------------
// 64x64 tile, 4 waves each owning a 32x32 quadrant. TWO independent acc
// chains (ks 0-1 vs 2-3) -> 2-way MFMA ILP at 1 wave/SIMD occupancy.
// BK=64, double-buffered LDS, register prefetch, one barrier per K-iter.
__global__ __launch_bounds__(256) void gemm_kernel(
    const unsigned short* __restrict__ A, const unsigned short* __restrict__ Wb,
    const float* __restrict__ bias, float* __restrict__ out) {
    const int n0 = blockIdx.x * 64;
    const int m0 = blockIdx.y * 64;

    __shared__ unsigned short As[2][64][72];  // +8 pad: row stride 144 B (bank-clean)
    __shared__ unsigned short Bs[2][64][72];

    const int t = threadIdx.x;
    const int lane = t & 63;
    const int wave = t >> 6;
    const int wm = (wave & 1) * 32;
    const int wn = (wave >> 1) * 32;

    const int lr = t >> 2, lq = t & 3;   // staging: 4 thr/row, 32 shorts each
    const unsigned short* ap = A  + (size_t)(m0 + lr) * H_DIM + lq * 16;
    const unsigned short* bp = Wb + (size_t)(n0 + lr) * H_DIM + lq * 16;

    f32x16 acc0 = {0.f,0.f,0.f,0.f,0.f,0.f,0.f,0.f,
                   0.f,0.f,0.f,0.f,0.f,0.f,0.f,0.f};
    f32x16 acc1 = {0.f,0.f,0.f,0.f,0.f,0.f,0.f,0.f,
                   0.f,0.f,0.f,0.f,0.f,0.f,0.f,0.f};

    const int row = lane & 31;
    const int hi = lane >> 5;

    uint4 a0 = *(const uint4*)(ap);
    uint4 a1 = *(const uint4*)(ap + 8);
    uint4 b0 = *(const uint4*)(bp);
    uint4 b1 = *(const uint4*)(bp + 8);
    *(uint4*)&As[0][lr][lq * 16]     = a0;
    *(uint4*)&As[0][lr][lq * 16 + 8] = a1;
    *(uint4*)&Bs[0][lr][lq * 16]     = b0;
    *(uint4*)&Bs[0][lr][lq * 16 + 8] = b1;
    __syncthreads();

    for (int ki = 0; ki < 32; ++ki) {
        const int cur = ki & 1, nxt = cur ^ 1;
        if (ki + 1 < 32) {  // prefetch next K-tile into registers
            a0 = *(const uint4*)(ap + (ki + 1) * 64);
            a1 = *(const uint4*)(ap + (ki + 1) * 64 + 8);
            b0 = *(const uint4*)(bp + (ki + 1) * 64);
            b1 = *(const uint4*)(bp + (ki + 1) * 64 + 8);
        }
        #pragma unroll
        for (int ks = 0; ks < 2; ++ks) {
            bf16x8 afA = *(const bf16x8*)&As[cur][wm + row][ks * 16 + hi * 8];
            bf16x8 bfA = *(const bf16x8*)&Bs[cur][wn + row][ks * 16 + hi * 8];
            acc0 = __builtin_amdgcn_mfma_f32_32x32x16_bf16(afA, bfA, acc0, 0, 0, 0);
            bf16x8 afB = *(const bf16x8*)&As[cur][wm + row][(ks + 2) * 16 + hi * 8];
            bf16x8 bfB = *(const bf16x8*)&Bs[cur][wn + row][(ks + 2) * 16 + hi * 8];
            acc1 = __builtin_amdgcn_mfma_f32_32x32x16_bf16(afB, bfB, acc1, 0, 0, 0);
        }
        if (ki + 1 < 32) {
            *(uint4*)&As[nxt][lr][lq * 16]     = a0;
            *(uint4*)&As[nxt][lr][lq * 16 + 8] = a1;
            *(uint4*)&Bs[nxt][lr][lq * 16]     = b0;
            *(uint4*)&Bs[nxt][lr][lq * 16 + 8] = b1;
        }
        __syncthreads();
    }

    // D mapping (32x32, m74/m101): col = lane&31 (N), row = (r&3)+8*(r>>2)+4*hi (M)
    const int col = lane & 31;
    const float bias0 = bias[n0 + wn + col];
    #pragma unroll
    for (int r = 0; r < 16; ++r) {
        const int mr = (r & 3) + 8 * (r >> 2) + 4 * hi;
        out[(size_t)(m0 + wm + mr) * H_DIM + n0 + wn + col] = acc0[r] + acc1[r] + bias0;
    }
}

extern "C" void kernel_launch(void* const* d_in, const int* in_sizes, int n_in,
                              void* d_out, int out_size, void* d_ws, size_t ws_size,
                              hipStream_t stream) {
    const float* OG   = (const float*)d_in[0];
    const float* E    = (const float*)d_in[1];
    const float* W    = (const float*)d_in[2];
    const float* bias = (const float*)d_in[3];
    float* out = (float*)d_out;

    unsigned short* wrep = (unsigned short*)d_ws;                 // 2 MiB bf16
    unsigned short* Wb   = wrep + (size_t)B_DIM * H_DIM;          // 8 MiB bf16

    fused_kernel<<<B_DIM, 512, 0, stream>>>(OG, E, W, wrep, Wb);
    gemm_kernel<<<dim3(H_DIM / 64, B_DIM / 64), 256, 0, stream>>>(wrep, Wb, bias, out);
}

// Round 4
// 124.781 us; speedup vs baseline: 1.1320x; 1.0106x over previous
//
#include <hip/hip_runtime.h>

#define S_DIM 16
#define B_DIM 512
#define H_DIM 2048
#define EPS 1e-8f

typedef short bf16x8 __attribute__((ext_vector_type(8)));
typedef float f32x16 __attribute__((ext_vector_type(16)));

__device__ __forceinline__ unsigned short f2bf(float f) {
    union { float f; unsigned int u; } v; v.f = f;
    unsigned int u = v.u;
    unsigned int r = (u + 0x7fffu + ((u >> 16) & 1u)) >> 16;
    return (unsigned short)r;
}

__device__ __forceinline__ float dot4(const float4& a, const float4& b) {
    return a.x*b.x + a.y*b.y + a.z*b.z + a.w*b.w;
}

// ---------------- Kernel A: fused sims + weighted mean -> wrep, W->bf16 ----------------
// One block per b (512 thr), wave w owns E rows s=w and s=w+8. W-convert loads
// issue FIRST (half before, half after the E burst) so the conversion overlaps
// the E stream instead of running as a serial tail. OG staged via LDS (low
// VGPR -> 2 blocks/CU). Barrier 1: ogs+red ready. Barrier 2: cross-wave sum.
__global__ __launch_bounds__(512, 4) void fused_kernel(
    const float* __restrict__ OG, const float* __restrict__ E,
    const float* __restrict__ W, unsigned short* __restrict__ wrep,
    unsigned short* __restrict__ Wb) {
    const int b = blockIdx.x;
    const int t = threadIdx.x;
    const int lane = t & 63;
    const int wave = t >> 6;

    __shared__ float4 buf[8][512];   // 64 KiB
    __shared__ float4 ogs[512];      // 8 KiB
    __shared__ float red[8];

    const float4* w4 = (const float4*)W;
    ushort4* wb4 = (ushort4*)Wb;
    const size_t wbase = (size_t)b * 2048 + t;

    // W first half + OG issue first (oldest in vmcnt queue)
    float4 wv0 = w4[wbase];
    float4 wv1 = w4[wbase + 512];
    const float4* og4 = (const float4*)(OG + (size_t)b * H_DIM);
    float4 o = og4[t];

    // E burst (16 float4 / lane)
    const float4* e4a = (const float4*)(E + ((size_t)wave * B_DIM + b) * H_DIM);
    const float4* e4b = (const float4*)(E + ((size_t)(wave + 8) * B_DIM + b) * H_DIM);
    float4 ea[8], eb[8];
    #pragma unroll
    for (int i = 0; i < 8; ++i) {
        ea[i] = e4a[i * 64 + lane];
        eb[i] = e4b[i * 64 + lane];
    }
    // W second half (in flight during E compute)
    float4 wv2 = w4[wbase + 1024];
    float4 wv3 = w4[wbase + 1536];

    // OG share + per-wave |OG|^2 partial
    ogs[t] = o;
    float p = dot4(o, o);
    #pragma unroll
    for (int m = 32; m >= 1; m >>= 1) p += __shfl_xor(p, m, 64);
    if (lane == 0) red[wave] = p;

    // convert W first half while E still lands (waits only wv0/wv1)
    {
        ushort4 c0, c1;
        c0.x = f2bf(wv0.x); c0.y = f2bf(wv0.y); c0.z = f2bf(wv0.z); c0.w = f2bf(wv0.w);
        c1.x = f2bf(wv1.x); c1.y = f2bf(wv1.y); c1.z = f2bf(wv1.z); c1.w = f2bf(wv1.w);
        wb4[wbase] = c0;
        wb4[wbase + 512] = c1;
    }
    __syncthreads();

    float og2 = 0.f;
    #pragma unroll
    for (int w = 0; w < 8; ++w) og2 += red[w];
    const float onorm = sqrtf(og2);

    float da = 0.f, na = 0.f, db = 0.f, nb = 0.f;
    #pragma unroll
    for (int i = 0; i < 8; ++i) {
        float4 g = ogs[i * 64 + lane];
        da += dot4(ea[i], g); na += dot4(ea[i], ea[i]);
        db += dot4(eb[i], g); nb += dot4(eb[i], eb[i]);
    }
    #pragma unroll
    for (int m = 32; m >= 1; m >>= 1) {
        da += __shfl_xor(da, m, 64);
        na += __shfl_xor(na, m, 64);
        db += __shfl_xor(db, m, 64);
        nb += __shfl_xor(nb, m, 64);
    }
    const float sima = da / fmaxf(sqrtf(na) * onorm, EPS);
    const float simb = db / fmaxf(sqrtf(nb) * onorm, EPS);

    #pragma unroll
    for (int i = 0; i < 8; ++i) {
        float4 v;
        v.x = ea[i].x * sima + eb[i].x * simb;
        v.y = ea[i].y * sima + eb[i].y * simb;
        v.z = ea[i].z * sima + eb[i].z * simb;
        v.w = ea[i].w * sima + eb[i].w * simb;
        buf[wave][i * 64 + lane] = v;
    }
    // convert W second half (arrived during compute)
    {
        ushort4 c2, c3;
        c2.x = f2bf(wv2.x); c2.y = f2bf(wv2.y); c2.z = f2bf(wv2.z); c2.w = f2bf(wv2.w);
        c3.x = f2bf(wv3.x); c3.y = f2bf(wv3.y); c3.z = f2bf(wv3.z); c3.w = f2bf(wv3.w);
        wb4[wbase + 1024] = c2;
        wb4[wbase + 1536] = c3;
    }
    __syncthreads();

    float4 s = buf[0][t];
    #pragma unroll
    for (int w = 1; w < 8; ++w) {
        float4 v = buf[w][t];
        s.x += v.x; s.y += v.y; s.z += v.z; s.w += v.w;
    }
    const float sc = 1.f / (float)S_DIM;
    ushort4 ob;
    ob.x = f2bf(s.x * sc); ob.y = f2bf(s.y * sc);
    ob.z = f2bf(s.z * sc); ob.w = f2bf(s.w * sc);
    ((ushort4*)wrep)[(size_t)b * (H_DIM / 4) + t] = ob;
}

// ---------------- Kernel C: out = wrep @ Wb^T + b  (bf16 MFMA 32x32x16) ----------------
// 64x64 tile, 4 waves, dual acc chains. 2-DEEP register pipeline: at iter k,
// issue loads for k+2, compute k from LDS, write k+1 to the other LDS buffer
// -> each global load gets a ~2-iteration latency window (counted vmcnt).
// LDS XOR-swizzle (byte ^= (row&7)<<4 on top of +8 pad) kills the 4-way
// ds_read_b128 conflict. XCD-pinned 1-D grid: m0 = bid&7 -> A panel (256 KiB)
// stays L2-resident per XCD.
__global__ __launch_bounds__(256) void gemm_kernel(
    const unsigned short* __restrict__ A, const unsigned short* __restrict__ Wb,
    const float* __restrict__ bias, float* __restrict__ out) {
    const int bid = blockIdx.x;
    const int m0 = (bid & 7) * 64;
    const int n0 = (bid >> 3) * 64;

    __shared__ unsigned short As[2][64 * 72];  // row stride 72 shorts = 144 B
    __shared__ unsigned short Bs[2][64 * 72];

    const int t = threadIdx.x;
    const int lane = t & 63;
    const int wave = t >> 6;
    const int wm = (wave & 1) * 32;
    const int wn = (wave >> 1) * 32;

    const int lr = t >> 2, lq = t & 3;   // staging: 4 thr/row, 32 shorts each
    const unsigned short* ap = A  + (size_t)(m0 + lr) * H_DIM + lq * 16;
    const unsigned short* bp = Wb + (size_t)(n0 + lr) * H_DIM + lq * 16;

    // swizzled write offsets (short units): byte = lq*32 (+16) XOR (lr&7)<<4
    const int sw = (lr & 7) << 4;
    const int w0 = lr * 72 + (((lq * 32) ^ sw) >> 1);
    const int w1 = lr * 72 + (((lq * 32 + 16) ^ sw) >> 1);

    f32x16 acc0 = {0.f,0.f,0.f,0.f,0.f,0.f,0.f,0.f,
                   0.f,0.f,0.f,0.f,0.f,0.f,0.f,0.f};
    f32x16 acc1 = {0.f,0.f,0.f,0.f,0.f,0.f,0.f,0.f,
                   0.f,0.f,0.f,0.f,0.f,0.f,0.f,0.f};

    const int row = lane & 31;
    const int hi = lane >> 5;
    // swizzled read offsets (short units) for the 4 fragments (ks=0..3)
    const int rbase = (wm + row) * 72;
    const int rsw = ((row & 7) << 4);
    int roffA[4], roffB[4];
    #pragma unroll
    for (int ks = 0; ks < 4; ++ks) {
        const int x = (ks * 32 + hi * 16) ^ rsw;
        roffA[ks] = rbase + (x >> 1);
        roffB[ks] = (wn + row) * 72 + (x >> 1);
    }

    // prologue: T0 -> r-set, T1 -> s-set, write T0 to buf0
    uint4 ra0 = *(const uint4*)(ap);
    uint4 ra1 = *(const uint4*)(ap + 8);
    uint4 rb0 = *(const uint4*)(bp);
    uint4 rb1 = *(const uint4*)(bp + 8);
    uint4 sa0 = *(const uint4*)(ap + 64);
    uint4 sa1 = *(const uint4*)(ap + 72);
    uint4 sb0 = *(const uint4*)(bp + 64);
    uint4 sb1 = *(const uint4*)(bp + 72);
    *(uint4*)&As[0][w0] = ra0;
    *(uint4*)&As[0][w1] = ra1;
    *(uint4*)&Bs[0][w0] = rb0;
    *(uint4*)&Bs[0][w1] = rb1;
    __syncthreads();

    #define MFMA_TILE(BUF)                                                        \
    {                                                                             \
        _Pragma("unroll")                                                         \
        for (int ks = 0; ks < 2; ++ks) {                                          \
            bf16x8 afA = *(const bf16x8*)&As[BUF][roffA[ks]];                     \
            bf16x8 bfA = *(const bf16x8*)&Bs[BUF][roffB[ks]];                     \
            acc0 = __builtin_amdgcn_mfma_f32_32x32x16_bf16(afA, bfA, acc0, 0,0,0);\
            bf16x8 afB = *(const bf16x8*)&As[BUF][roffA[ks + 2]];                 \
            bf16x8 bfB = *(const bf16x8*)&Bs[BUF][roffB[ks + 2]];                 \
            acc1 = __builtin_amdgcn_mfma_f32_32x32x16_bf16(afB, bfB, acc1, 0,0,0);\
        }                                                                         \
    }

    for (int ki = 0; ki < 32; ki += 2) {
        // ---- even sub-iter: compute T_ki from buf0; T_{ki+1} is in s-set ----
        if (ki + 2 < 32) {  // issue T_{ki+2} into freed r-set
            ra0 = *(const uint4*)(ap + (ki + 2) * 64);
            ra1 = *(const uint4*)(ap + (ki + 2) * 64 + 8);
            rb0 = *(const uint4*)(bp + (ki + 2) * 64);
            rb1 = *(const uint4*)(bp + (ki + 2) * 64 + 8);
        }
        MFMA_TILE(0);
        *(uint4*)&As[1][w0] = sa0;   // T_{ki+1} (waits its 4 loads, counted)
        *(uint4*)&As[1][w1] = sa1;
        *(uint4*)&Bs[1][w0] = sb0;
        *(uint4*)&Bs[1][w1] = sb1;
        __syncthreads();
        // ---- odd sub-iter: compute T_{ki+1} from buf1; T_{ki+2} in r-set ----
        if (ki + 3 < 32) {  // issue T_{ki+3} into freed s-set
            sa0 = *(const uint4*)(ap + (ki + 3) * 64);
            sa1 = *(const uint4*)(ap + (ki + 3) * 64 + 8);
            sb0 = *(const uint4*)(bp + (ki + 3) * 64);
            sb1 = *(const uint4*)(bp + (ki + 3) * 64 + 8);
        }
        MFMA_TILE(1);
        if (ki + 2 < 32) {
            *(uint4*)&As[0][w0] = ra0;   // T_{ki+2}
            *(uint4*)&As[0][w1] = ra1;
            *(uint4*)&Bs[0][w0] = rb0;
            *(uint4*)&Bs[0][w1] = rb1;
            __syncthreads();
        }
    }
    #undef MFMA_TILE

    // D mapping (32x32, m74/m101): col = lane&31 (N), row = (r&3)+8*(r>>2)+4*hi (M)
    const int col = lane & 31;
    const float bias0 = bias[n0 + wn + col];
    #pragma unroll
    for (int r = 0; r < 16; ++r) {
        const int mr = (r & 3) + 8 * (r >> 2) + 4 * hi;
        out[(size_t)(m0 + wm + mr) * H_DIM + n0 + wn + col] = acc0[r] + acc1[r] + bias0;
    }
}

extern "C" void kernel_launch(void* const* d_in, const int* in_sizes, int n_in,
                              void* d_out, int out_size, void* d_ws, size_t ws_size,
                              hipStream_t stream) {
    const float* OG   = (const float*)d_in[0];
    const float* E    = (const float*)d_in[1];
    const float* W    = (const float*)d_in[2];
    const float* bias = (const float*)d_in[3];
    float* out = (float*)d_out;

    unsigned short* wrep = (unsigned short*)d_ws;                 // 2 MiB bf16
    unsigned short* Wb   = wrep + (size_t)B_DIM * H_DIM;          // 8 MiB bf16

    fused_kernel<<<B_DIM, 512, 0, stream>>>(OG, E, W, wrep, Wb);
    gemm_kernel<<<256, 256, 0, stream>>>(wrep, Wb, bias, out);
}